// Round 5
// baseline (192.491 us; speedup 1.0000x reference)
//
#include <hip/hip_runtime.h>
#include <math.h>

#define TSIZE (1u << 20)
#define PRIME_Y 2654435761u
#define NHASH 6   // hashed levels 6..11

typedef __attribute__((ext_vector_type(8))) short short8;     // bf16x8 MFMA frag
typedef __attribute__((ext_vector_type(4))) float f32x4;      // MFMA acc frag
typedef __attribute__((ext_vector_type(4))) float float4v;
typedef __attribute__((ext_vector_type(4))) unsigned uint4v;
typedef __attribute__((ext_vector_type(2))) unsigned uint2v;

__device__ __forceinline__ unsigned bf16rne(unsigned u) {
    return (u + 0x7fffu + ((u >> 16) & 1u)) >> 16;   // RNE to bf16 (in low 16)
}
__device__ __forceinline__ unsigned pack_bf16x2(float a, float b) {
    return (bf16rne(__float_as_uint(a)) & 0xffffu) | (bf16rne(__float_as_uint(b)) << 16);
}
__device__ __forceinline__ float2 unpack_bf16x2(unsigned u) {
    float2 r;
    r.x = __uint_as_float(u << 16);
    r.y = __uint_as_float(u & 0xffff0000u);
    return r;
}
__device__ __forceinline__ short f2bf(float x) {
    return (short)(bf16rne(__float_as_uint(x)) & 0xffffu);
}
__device__ __forceinline__ float bf2f(short h) {
    return __uint_as_float(((unsigned)(unsigned short)h) << 16);
}

// ---- pass 0: convert hashed-level tables (f32 float2) -> packed bf16x2 in ws
__global__ __launch_bounds__(256) void convert_kernel(const float* __restrict__ table,
                                                      unsigned* __restrict__ wtab) {
    const size_t total4 = (size_t)NHASH * TSIZE / 2;   // float4 chunks (2 entries)
    const float4v* __restrict__ src =
        reinterpret_cast<const float4v*>(table + (size_t)6 * TSIZE * 2);
    uint2v* __restrict__ dst = reinterpret_cast<uint2v*>(wtab);
    for (size_t i = (size_t)blockIdx.x * 256 + threadIdx.x; i < total4;
         i += (size_t)gridDim.x * 256) {
        float4v v = __builtin_nontemporal_load(&src[i]);
        uint2v o;
        o.x = pack_bf16x2(v.x, v.y);
        o.y = pack_bf16x2(v.z, v.w);
        __builtin_nontemporal_store(o, &dst[i]);
    }
}

// ---- setup: build per-lane MFMA B-fragments once (64 lanes, 1 block).
// Layout wfrag[f][lane] as uint4 (f = 0:bf0 1:b1a 2:b1b 3:b2a 4:b2b 5:biases)
// hi/lo interleaved K=32 convention: A[2i]=hi_i, A[2i+1]=lo_i, so
// Ba[k]=Whi_i always, Bb[k] = (k even) ? Wlo_i : 0.
__global__ __launch_bounds__(64) void setup_kernel(
    const float* __restrict__ W0, const float* __restrict__ b0,
    const float* __restrict__ W1, const float* __restrict__ b1,
    const float* __restrict__ W2, const float* __restrict__ b2,
    const float* __restrict__ W3,
    uint4v* __restrict__ wfrag)
{
    const int lane = threadIdx.x;
    const int n = lane & 15;
    const int kb = lane >> 4;
    short8 bf0, b1a, b1b, b2a, b2b;
    #pragma unroll
    for (int j = 0; j < 8; ++j) {
        const int k = kb * 8 + j;
        bf0[j] = (k < 24) ? f2bf(W0[k * 16 + n]) : (short)0;
        const int i = k >> 1;
        const float w1 = W1[i * 16 + n];
        const float w2 = W2[i * 16 + n];
        const short w1h = f2bf(w1), w2h = f2bf(w2);
        b1a[j] = w1h;
        b2a[j] = w2h;
        b1b[j] = (k & 1) ? (short)0 : f2bf(w1 - bf2f(w1h));
        b2b[j] = (k & 1) ? (short)0 : f2bf(w2 - bf2f(w2h));
    }
    union { short8 s; uint4v u; } cv;
    cv.s = bf0; wfrag[0 * 64 + lane] = cv.u;
    cv.s = b1a; wfrag[1 * 64 + lane] = cv.u;
    cv.s = b1b; wfrag[2 * 64 + lane] = cv.u;
    cv.s = b2a; wfrag[3 * 64 + lane] = cv.u;
    cv.s = b2b; wfrag[4 * 64 + lane] = cv.u;
    float4v bb;
    bb.x = b0[n]; bb.y = b1[n]; bb.z = b2[n]; bb.w = W3[n];
    union { float4v f; uint4v u; } cf; cf.f = bb;
    wfrag[5 * 64 + lane] = cf.u;
}

// ---- per-level gather pass: one hashed level, 4 consecutive points/thread.
__global__ __launch_bounds__(256) void pass_kernel(const float* __restrict__ coords,
                                                   const unsigned* __restrict__ wtab,
                                                   unsigned* __restrict__ wenc,
                                                   int lvl, int N) {
    const int gid = blockIdx.x * 256 + threadIdx.x;
    const int base = gid * 4;
    if (base >= N) return;
    const int res = 16 << (lvl + 6);
    const unsigned* __restrict__ tl = wtab + (size_t)lvl * TSIZE;
    unsigned* __restrict__ we = wenc + (size_t)lvl * N;

    if (base + 3 < N) {
        const float4v* __restrict__ c4 = reinterpret_cast<const float4v*>(coords);
        const float4v ca = c4[gid * 2];
        const float4v cb = c4[gid * 2 + 1];
        const float xs[4] = {ca.x, ca.z, cb.x, cb.z};
        const float ys[4] = {ca.y, ca.w, cb.y, cb.w};
        unsigned hidx[16];
        float wxs[4], wys[4];
        #pragma unroll
        for (int p = 0; p < 4; ++p) {
            const float px = xs[p] * (float)res;
            const float py = ys[p] * (float)res;
            const float fx = floorf(px), fy = floorf(py);
            wxs[p] = px - fx;
            wys[p] = py - fy;
            const unsigned ux = (unsigned)(int)fx, uy = (unsigned)(int)fy;
            const unsigned hy0 = uy * PRIME_Y;
            const unsigned hy1 = (uy + 1u) * PRIME_Y;
            hidx[p * 4 + 0] = (ux ^ hy0) & (TSIZE - 1u);
            hidx[p * 4 + 1] = ((ux + 1u) ^ hy0) & (TSIZE - 1u);
            hidx[p * 4 + 2] = (ux ^ hy1) & (TSIZE - 1u);
            hidx[p * 4 + 3] = ((ux + 1u) ^ hy1) & (TSIZE - 1u);
        }
        unsigned v[16];
        #pragma unroll
        for (int q = 0; q < 16; ++q) v[q] = tl[hidx[q]];   // 16 outstanding gathers
        uint4v r;
        #pragma unroll
        for (int p = 0; p < 4; ++p) {
            const float wx = wxs[p], wy = wys[p];
            const float w00 = (1.0f - wx) * (1.0f - wy);
            const float w10 = wx * (1.0f - wy);
            const float w01 = (1.0f - wx) * wy;
            const float w11 = wx * wy;
            const float2 v00 = unpack_bf16x2(v[p * 4 + 0]);
            const float2 v10 = unpack_bf16x2(v[p * 4 + 1]);
            const float2 v01 = unpack_bf16x2(v[p * 4 + 2]);
            const float2 v11 = unpack_bf16x2(v[p * 4 + 3]);
            const float e0 = v00.x * w00 + v10.x * w10 + v01.x * w01 + v11.x * w11;
            const float e1 = v00.y * w00 + v10.y * w10 + v01.y * w01 + v11.y * w11;
            r[p] = pack_bf16x2(e0, e1);
        }
        __builtin_nontemporal_store(r, &((uint4v*)we)[gid]);
    } else {
        for (int p = 0; p < 4 && base + p < N; ++p) {
            const float2 c = reinterpret_cast<const float2*>(coords)[base + p];
            const float px = c.x * (float)res;
            const float py = c.y * (float)res;
            const float fx = floorf(px), fy = floorf(py);
            const float wx = px - fx, wy = py - fy;
            const unsigned ux = (unsigned)(int)fx, uy = (unsigned)(int)fy;
            const unsigned hy0 = uy * PRIME_Y;
            const unsigned hy1 = (uy + 1u) * PRIME_Y;
            const float2 v00 = unpack_bf16x2(tl[(ux ^ hy0) & (TSIZE - 1u)]);
            const float2 v10 = unpack_bf16x2(tl[((ux + 1u) ^ hy0) & (TSIZE - 1u)]);
            const float2 v01 = unpack_bf16x2(tl[(ux ^ hy1) & (TSIZE - 1u)]);
            const float2 v11 = unpack_bf16x2(tl[((ux + 1u) ^ hy1) & (TSIZE - 1u)]);
            const float w00 = (1.0f - wx) * (1.0f - wy);
            const float w10 = wx * (1.0f - wy);
            const float w01 = (1.0f - wx) * wy;
            const float w11 = wx * wy;
            const float e0 = v00.x * w00 + v10.x * w10 + v01.x * w01 + v11.x * w11;
            const float e1 = v00.y * w00 + v10.y * w10 + v01.y * w01 + v11.y * w11;
            we[base + p] = pack_bf16x2(e0, e1);
        }
    }
}

// ---- final: dense levels + hashed enc from ws + MFMA SIREN MLP.
// 64-thread blocks (single wave): barriers retire immediately.
// A-frag row=lane&15, k=(lane>>4)*8+j; D: col=lane&15, row=(lane>>4)*4+reg.
__global__ __launch_bounds__(64) void mlp_kernel(
    const float* __restrict__ coords,
    const float* __restrict__ table,
    const unsigned* __restrict__ wenc,
    const uint4v* __restrict__ wfrag,
    const float* __restrict__ b3p,
    float* __restrict__ out, int N)
{
    __shared__ char lds[5120];              // 64 rows x 80 B
    const int lane = threadIdx.x;
    const int n = lane & 15;
    const int kb = lane >> 4;

    // B-fragments: 6 coalesced b128 loads (built once by setup_kernel)
    union { short8 s; uint4v u; } c0, c1, c2, c3, c4;
    c0.u = wfrag[0 * 64 + lane];
    c1.u = wfrag[1 * 64 + lane];
    c2.u = wfrag[2 * 64 + lane];
    c3.u = wfrag[3 * 64 + lane];
    c4.u = wfrag[4 * 64 + lane];
    const short8 bf0 = c0.s, b1a = c1.s, b1b = c2.s, b2a = c3.s, b2b = c4.s;
    union { float4v f; uint4v u; } cf;
    cf.u = wfrag[5 * 64 + lane];
    const float b0n = cf.f.x, b1n = cf.f.y, b2n = cf.f.z, w3n = cf.f.w;
    const float b3s = b3p[0];

    const int idx = blockIdx.x * 64 + lane;
    const int idxc = (idx < N) ? idx : (N - 1);

    // hashed-enc streaming loads first (stay in flight over dense interp)
    unsigned he[NHASH];
    #pragma unroll
    for (int l = 0; l < NHASH; ++l)
        he[l] = __builtin_nontemporal_load(&wenc[(size_t)l * N + idxc]);

    const float2 c = reinterpret_cast<const float2*>(coords)[idxc];

    float enc[24];
    #pragma unroll
    for (int lvl = 0; lvl < 6; ++lvl) {
        const int res = 16 << lvl;
        const float px = c.x * (float)res;
        const float py = c.y * (float)res;
        const float fx = floorf(px), fy = floorf(py);
        const float wx = px - fx, wy = py - fy;
        const int ix = (int)fx, iy = (int)fy;
        const int stride = res + 1;
        const int base = ix + iy * stride;
        const float2* __restrict__ tl =
            reinterpret_cast<const float2*>(table) + (size_t)lvl * TSIZE;
        const float2 v00 = tl[base];
        const float2 v10 = tl[base + 1];
        const float2 v01 = tl[base + stride];
        const float2 v11 = tl[base + stride + 1];
        const float w00 = (1.0f - wx) * (1.0f - wy);
        const float w10 = wx * (1.0f - wy);
        const float w01 = (1.0f - wx) * wy;
        const float w11 = wx * wy;
        enc[2 * lvl]     = v00.x * w00 + v10.x * w10 + v01.x * w01 + v11.x * w11;
        enc[2 * lvl + 1] = v00.y * w00 + v10.y * w10 + v01.y * w01 + v11.y * w11;
    }
    #pragma unroll
    for (int l = 0; l < NHASH; ++l) {
        const float2 v = unpack_bf16x2(he[l]);
        enc[12 + 2 * l]     = v.x;
        enc[12 + 2 * l + 1] = v.y;
    }

    // ---- stage enc as bf16, K padded 24->32, row = lane (80 B stride)
    unsigned u[12];
    #pragma unroll
    for (int k = 0; k < 12; ++k) u[k] = pack_bf16x2(enc[2 * k], enc[2 * k + 1]);
    {
        uint4v* rowp = (uint4v*)(lds + lane * 80);
        uint4v r0; r0.x = u[0]; r0.y = u[1]; r0.z = u[2]; r0.w = u[3];
        uint4v r1; r1.x = u[4]; r1.y = u[5]; r1.z = u[6]; r1.w = u[7];
        uint4v r2; r2.x = u[8]; r2.y = u[9]; r2.z = u[10]; r2.w = u[11];
        uint4v r3; r3.x = 0u; r3.y = 0u; r3.z = 0u; r3.w = 0u;  // keep: no NaN*0
        rowp[0] = r0; rowp[1] = r1; rowp[2] = r2; rowp[3] = r3;
    }
    __syncthreads();

    short8 a[4];
    #pragma unroll
    for (int m = 0; m < 4; ++m)
        a[m] = *(const short8*)(lds + (m * 16 + n) * 80 + kb * 16);
    __syncthreads();

    const f32x4 z = {0.f, 0.f, 0.f, 0.f};
    f32x4 acc[4];
    #pragma unroll
    for (int m = 0; m < 4; ++m)
        acc[m] = __builtin_amdgcn_mfma_f32_16x16x32_bf16(a[m], bf0, z, 0, 0, 0);

    unsigned* hp32 = (unsigned*)lds;   // rows of 20 words; word n = {hi_n | lo_n<<16}

    // ---- layer 1: h0 = sin(300*(acc+b0)); packed hi|lo write; mfma hi+lo
    #pragma unroll
    for (int m = 0; m < 4; ++m) {
        #pragma unroll
        for (int r = 0; r < 4; ++r) {
            const float v = __sinf(300.0f * (acc[m][r] + b0n));
            const short hi = f2bf(v);
            const short lo = f2bf(v - bf2f(hi));
            const int row = m * 16 + kb * 4 + r;
            hp32[row * 20 + n] =
                ((unsigned)(unsigned short)hi) | (((unsigned)(unsigned short)lo) << 16);
        }
    }
    __syncthreads();
    #pragma unroll
    for (int m = 0; m < 4; ++m)
        a[m] = *(const short8*)(lds + (m * 16 + n) * 80 + kb * 16);
    __syncthreads();
    #pragma unroll
    for (int m = 0; m < 4; ++m) {
        f32x4 p = __builtin_amdgcn_mfma_f32_16x16x32_bf16(a[m], b1a, z, 0, 0, 0);
        acc[m] = __builtin_amdgcn_mfma_f32_16x16x32_bf16(a[m], b1b, p, 0, 0, 0);
    }

    // ---- layer 2
    #pragma unroll
    for (int m = 0; m < 4; ++m) {
        #pragma unroll
        for (int r = 0; r < 4; ++r) {
            const float v = __sinf(acc[m][r] + b1n);
            const short hi = f2bf(v);
            const short lo = f2bf(v - bf2f(hi));
            const int row = m * 16 + kb * 4 + r;
            hp32[row * 20 + n] =
                ((unsigned)(unsigned short)hi) | (((unsigned)(unsigned short)lo) << 16);
        }
    }
    __syncthreads();
    #pragma unroll
    for (int m = 0; m < 4; ++m)
        a[m] = *(const short8*)(lds + (m * 16 + n) * 80 + kb * 16);
    __syncthreads();
    #pragma unroll
    for (int m = 0; m < 4; ++m) {
        f32x4 p = __builtin_amdgcn_mfma_f32_16x16x32_bf16(a[m], b2a, z, 0, 0, 0);
        acc[m] = __builtin_amdgcn_mfma_f32_16x16x32_bf16(a[m], b2b, p, 0, 0, 0);
    }

    // ---- layer 3 (final, 16->1) in f32: h2 = sin(acc+b2); o = h2@W3 + b3
    float red[4][4];
    #pragma unroll
    for (int m = 0; m < 4; ++m) {
        #pragma unroll
        for (int r = 0; r < 4; ++r) {
            float v = __sinf(acc[m][r] + b2n) * w3n;
            v += __shfl_xor(v, 1);
            v += __shfl_xor(v, 2);
            v += __shfl_xor(v, 4);
            v += __shfl_xor(v, 8);
            red[m][r] = v;     // identical across the 16 lanes of group kb
        }
    }
    const int m2 = n >> 2, r2 = n & 3;
    float ov = 0.f;
    #pragma unroll
    for (int m = 0; m < 4; ++m) {
        #pragma unroll
        for (int r = 0; r < 4; ++r)
            if (m == m2 && r == r2) ov = red[m][r];   // static idx -> cndmask
    }
    const int gidx = blockIdx.x * 64 + m2 * 16 + kb * 4 + r2;
    if (gidx < N) out[gidx] = ov + b3s;
}

// ---- fallback: R1 fused kernel (known-good) for small ws
__global__ __launch_bounds__(256) void hashsiren_fused(
    const float* __restrict__ coords,
    const float* __restrict__ table,
    const float* __restrict__ W0, const float* __restrict__ b0,
    const float* __restrict__ W1, const float* __restrict__ b1,
    const float* __restrict__ W2, const float* __restrict__ b2,
    const float* __restrict__ W3, const float* __restrict__ b3,
    float* __restrict__ out, int N)
{
    __shared__ float sW0[384];
    __shared__ float sW1[256];
    __shared__ float sW2[256];
    __shared__ float sb0[16], sb1[16], sb2[16], sW3[16];
    __shared__ float sb3;

    const int t = threadIdx.x;
    for (int i = t; i < 384; i += 256) sW0[i] = W0[i];
    sW1[t] = W1[t];
    sW2[t] = W2[t];
    if (t < 16) { sb0[t] = b0[t]; sb1[t] = b1[t]; sb2[t] = b2[t]; sW3[t] = W3[t]; }
    if (t == 0) sb3 = b3[0];
    __syncthreads();

    const int idx = blockIdx.x * 256 + t;
    if (idx >= N) return;

    const float2 c = reinterpret_cast<const float2*>(coords)[idx];

    float2 hv00[6], hv10[6], hv01[6], hv11[6];
    float hwx[6], hwy[6];
    #pragma unroll
    for (int l = 0; l < 6; ++l) {
        const int res = 16 << (l + 6);
        const float px = c.x * (float)res;
        const float py = c.y * (float)res;
        const float fx = floorf(px), fy = floorf(py);
        hwx[l] = px - fx;
        hwy[l] = py - fy;
        const unsigned ux = (unsigned)(int)fx, uy = (unsigned)(int)fy;
        const unsigned hy0 = uy * PRIME_Y;
        const unsigned hy1 = (uy + 1u) * PRIME_Y;
        const float2* __restrict__ tl =
            reinterpret_cast<const float2*>(table) + (size_t)(l + 6) * TSIZE;
        hv00[l] = tl[(ux ^ hy0) & (TSIZE - 1u)];
        hv10[l] = tl[((ux + 1u) ^ hy0) & (TSIZE - 1u)];
        hv01[l] = tl[(ux ^ hy1) & (TSIZE - 1u)];
        hv11[l] = tl[((ux + 1u) ^ hy1) & (TSIZE - 1u)];
    }

    float enc[24];
    #pragma unroll
    for (int lvl = 0; lvl < 6; ++lvl) {
        const int res = 16 << lvl;
        const float px = c.x * (float)res;
        const float py = c.y * (float)res;
        const float fx = floorf(px), fy = floorf(py);
        const float wx = px - fx, wy = py - fy;
        const int ix = (int)fx, iy = (int)fy;
        const int stride = res + 1;
        const int base = ix + iy * stride;
        const float2* __restrict__ tl =
            reinterpret_cast<const float2*>(table) + (size_t)lvl * TSIZE;
        const float2 v00 = tl[base];
        const float2 v10 = tl[base + 1];
        const float2 v01 = tl[base + stride];
        const float2 v11 = tl[base + stride + 1];
        const float w00 = (1.0f - wx) * (1.0f - wy);
        const float w10 = wx * (1.0f - wy);
        const float w01 = (1.0f - wx) * wy;
        const float w11 = wx * wy;
        enc[2 * lvl]     = v00.x * w00 + v10.x * w10 + v01.x * w01 + v11.x * w11;
        enc[2 * lvl + 1] = v00.y * w00 + v10.y * w10 + v01.y * w01 + v11.y * w11;
    }
    #pragma unroll
    for (int l = 0; l < 6; ++l) {
        const float wx = hwx[l], wy = hwy[l];
        const float w00 = (1.0f - wx) * (1.0f - wy);
        const float w10 = wx * (1.0f - wy);
        const float w01 = (1.0f - wx) * wy;
        const float w11 = wx * wy;
        enc[2 * (l + 6)]     = hv00[l].x * w00 + hv10[l].x * w10 + hv01[l].x * w01 + hv11[l].x * w11;
        enc[2 * (l + 6) + 1] = hv00[l].y * w00 + hv10[l].y * w10 + hv01[l].y * w01 + hv11[l].y * w11;
    }

    float h0[16];
    #pragma unroll
    for (int j = 0; j < 16; ++j) {
        float aa = sb0[j];
        #pragma unroll
        for (int k = 0; k < 24; ++k) aa += enc[k] * sW0[k * 16 + j];
        h0[j] = __sinf(300.0f * aa);
    }
    float h1[16];
    #pragma unroll
    for (int j = 0; j < 16; ++j) {
        float aa = sb1[j];
        #pragma unroll
        for (int k = 0; k < 16; ++k) aa += h0[k] * sW1[k * 16 + j];
        h1[j] = __sinf(aa);
    }
    float h2[16];
    #pragma unroll
    for (int j = 0; j < 16; ++j) {
        float aa = sb2[j];
        #pragma unroll
        for (int k = 0; k < 16; ++k) aa += h1[k] * sW2[k * 16 + j];
        h2[j] = __sinf(aa);
    }
    float o = sb3;
    #pragma unroll
    for (int k = 0; k < 16; ++k) o += h2[k] * sW3[k];
    out[idx] = o;
}

extern "C" void kernel_launch(void* const* d_in, const int* in_sizes, int n_in,
                              void* d_out, int out_size, void* d_ws, size_t ws_size,
                              hipStream_t stream) {
    const float* coords = (const float*)d_in[0];
    const float* table  = (const float*)d_in[1];
    const float* W0 = (const float*)d_in[2];
    const float* b0 = (const float*)d_in[3];
    const float* W1 = (const float*)d_in[4];
    const float* b1 = (const float*)d_in[5];
    const float* W2 = (const float*)d_in[6];
    const float* b2 = (const float*)d_in[7];
    const float* W3 = (const float*)d_in[8];
    const float* b3 = (const float*)d_in[9];
    float* out = (float*)d_out;

    const int N = in_sizes[0] / 2;  // coords is [N,2]

    const size_t tab_w = (size_t)NHASH * TSIZE;          // u32 words
    const size_t enc_w = (size_t)NHASH * (size_t)N;      // u32 words
    const size_t need = tab_w * 4 + enc_w * 4 + 6144;    // + wfrag
    if (ws_size >= need) {
        unsigned* wtab = (unsigned*)d_ws;
        unsigned* wenc = wtab + tab_w;
        uint4v* wfrag = (uint4v*)(wenc + enc_w);
        setup_kernel<<<1, 64, 0, stream>>>(W0, b0, W1, b1, W2, b2, W3, wfrag);
        convert_kernel<<<4096, 256, 0, stream>>>(table, wtab);
        const int pgrid = (N + 1023) / 1024;
        for (int l = 0; l < NHASH; ++l)
            pass_kernel<<<pgrid, 256, 0, stream>>>(coords, wtab, wenc, l, N);
        mlp_kernel<<<(N + 63) / 64, 64, 0, stream>>>(coords, table, wenc, wfrag,
                                                     b3, out, N);
    } else {
        const int block = 256;
        const int grid = (N + block - 1) / block;
        hashsiren_fused<<<grid, block, 0, stream>>>(coords, table,
                                                    W0, b0, W1, b1, W2, b2, W3, b3,
                                                    out, N);
    }
}

// Round 6
// 178.590 us; speedup vs baseline: 1.0778x; 1.0778x over previous
//
#include <hip/hip_runtime.h>
#include <math.h>

#define TSIZE (1u << 20)
#define PRIME_Y 2654435761u
#define NHASH 6   // hashed levels 6..11

typedef __attribute__((ext_vector_type(8))) short short8;     // bf16x8 MFMA frag
typedef __attribute__((ext_vector_type(4))) float f32x4;      // MFMA acc frag
typedef __attribute__((ext_vector_type(4))) float float4v;
typedef __attribute__((ext_vector_type(4))) unsigned uint4v;
typedef __attribute__((ext_vector_type(2))) unsigned uint2v;

struct alignas(8) f4a8 { float x, y, z, w; };   // 16B row load at 8B alignment

__device__ __forceinline__ unsigned bf16rne(unsigned u) {
    return (u + 0x7fffu + ((u >> 16) & 1u)) >> 16;   // RNE to bf16 (in low 16)
}
__device__ __forceinline__ unsigned pack_bf16x2(float a, float b) {
    return (bf16rne(__float_as_uint(a)) & 0xffffu) | (bf16rne(__float_as_uint(b)) << 16);
}
__device__ __forceinline__ float2 unpack_bf16x2(unsigned u) {
    float2 r;
    r.x = __uint_as_float(u << 16);
    r.y = __uint_as_float(u & 0xffff0000u);
    return r;
}
__device__ __forceinline__ short f2bf(float x) {
    return (short)(bf16rne(__float_as_uint(x)) & 0xffffu);
}
__device__ __forceinline__ float bf2f(short h) {
    return __uint_as_float(((unsigned)(unsigned short)h) << 16);
}

// ---- pass 0: convert hashed-level tables (f32 float2) -> packed bf16x2 in ws
__global__ __launch_bounds__(256) void convert_kernel(const float* __restrict__ table,
                                                      unsigned* __restrict__ wtab) {
    const size_t total4 = (size_t)NHASH * TSIZE / 2;   // float4 chunks (2 entries)
    const float4v* __restrict__ src =
        reinterpret_cast<const float4v*>(table + (size_t)6 * TSIZE * 2);
    uint2v* __restrict__ dst = reinterpret_cast<uint2v*>(wtab);
    for (size_t i = (size_t)blockIdx.x * 256 + threadIdx.x; i < total4;
         i += (size_t)gridDim.x * 256) {
        float4v v = __builtin_nontemporal_load(&src[i]);
        uint2v o;
        o.x = pack_bf16x2(v.x, v.y);
        o.y = pack_bf16x2(v.z, v.w);
        __builtin_nontemporal_store(o, &dst[i]);
    }
}

// ---- setup: build per-lane MFMA B-fragments once (64 lanes, 1 block).
__global__ __launch_bounds__(64) void setup_kernel(
    const float* __restrict__ W0, const float* __restrict__ b0,
    const float* __restrict__ W1, const float* __restrict__ b1,
    const float* __restrict__ W2, const float* __restrict__ b2,
    const float* __restrict__ W3,
    uint4v* __restrict__ wfrag)
{
    const int lane = threadIdx.x;
    const int n = lane & 15;
    const int kb = lane >> 4;
    short8 bf0, b1a, b1b, b2a, b2b;
    #pragma unroll
    for (int j = 0; j < 8; ++j) {
        const int k = kb * 8 + j;
        bf0[j] = (k < 24) ? f2bf(W0[k * 16 + n]) : (short)0;
        const int i = k >> 1;
        const float w1 = W1[i * 16 + n];
        const float w2 = W2[i * 16 + n];
        const short w1h = f2bf(w1), w2h = f2bf(w2);
        b1a[j] = w1h;
        b2a[j] = w2h;
        b1b[j] = (k & 1) ? (short)0 : f2bf(w1 - bf2f(w1h));
        b2b[j] = (k & 1) ? (short)0 : f2bf(w2 - bf2f(w2h));
    }
    union { short8 s; uint4v u; } cv;
    cv.s = bf0; wfrag[0 * 64 + lane] = cv.u;
    cv.s = b1a; wfrag[1 * 64 + lane] = cv.u;
    cv.s = b1b; wfrag[2 * 64 + lane] = cv.u;
    cv.s = b2a; wfrag[3 * 64 + lane] = cv.u;
    cv.s = b2b; wfrag[4 * 64 + lane] = cv.u;
    float4v bb;
    bb.x = b0[n]; bb.y = b1[n]; bb.z = b2[n]; bb.w = W3[n];
    union { float4v f; uint4v u; } cf; cf.f = bb;
    wfrag[5 * 64 + lane] = cf.u;
}

// ---- per-level gather pass: 4 consecutive points/thread, parity pair loads.
// When ux even: h10 = h00^1 -> both x-corners in one aligned uint2 (1 request).
// Odd-ux lanes issue the extra 4B loads exec-masked (no requests from even lanes).
__global__ __launch_bounds__(256) void pass_kernel(const float* __restrict__ coords,
                                                   const unsigned* __restrict__ wtab,
                                                   unsigned* __restrict__ wenc,
                                                   int lvl, int N) {
    const int gid = blockIdx.x * 256 + threadIdx.x;
    const int base = gid * 4;
    if (base >= N) return;
    const int res = 16 << (lvl + 6);
    const unsigned* __restrict__ tl = wtab + (size_t)lvl * TSIZE;
    const uint2v* __restrict__ tl2 = reinterpret_cast<const uint2v*>(tl);
    unsigned* __restrict__ we = wenc + (size_t)lvl * N;

    if (base + 3 < N) {
        const float4v* __restrict__ c4 = reinterpret_cast<const float4v*>(coords);
        const float4v ca = c4[gid * 2];
        const float4v cb = c4[gid * 2 + 1];
        const float xs[4] = {ca.x, ca.z, cb.x, cb.z};
        const float ys[4] = {ca.y, ca.w, cb.y, cb.w};
        unsigned h00a[4], h01a[4], h10a[4], h11a[4], oddp[4];
        float wxs[4], wys[4];
        #pragma unroll
        for (int p = 0; p < 4; ++p) {
            const float px = xs[p] * (float)res;
            const float py = ys[p] * (float)res;
            const float fx = floorf(px), fy = floorf(py);
            wxs[p] = px - fx;
            wys[p] = py - fy;
            const unsigned ux = (unsigned)(int)fx, uy = (unsigned)(int)fy;
            const unsigned hy0 = uy * PRIME_Y;
            const unsigned hy1 = (uy + 1u) * PRIME_Y;
            h00a[p] = (ux ^ hy0) & (TSIZE - 1u);
            h01a[p] = (ux ^ hy1) & (TSIZE - 1u);
            h10a[p] = ((ux + 1u) ^ hy0) & (TSIZE - 1u);
            h11a[p] = ((ux + 1u) ^ hy1) & (TSIZE - 1u);
            oddp[p] = ux & 1u;
        }
        // issue all pair loads (8 requests)
        uint2v pr0[4], pr1[4];
        #pragma unroll
        for (int p = 0; p < 4; ++p) {
            pr0[p] = tl2[h00a[p] >> 1];
            pr1[p] = tl2[h01a[p] >> 1];
        }
        // exec-masked extra loads for odd-ux lanes only
        unsigned t10[4], t11[4];
        #pragma unroll
        for (int p = 0; p < 4; ++p) { t10[p] = 0u; t11[p] = 0u; }
        #pragma unroll
        for (int p = 0; p < 4; ++p) {
            if (oddp[p]) {
                t10[p] = tl[h10a[p]];
                t11[p] = tl[h11a[p]];
            }
        }
        uint4v r;
        #pragma unroll
        for (int p = 0; p < 4; ++p) {
            const unsigned s0 = h00a[p] & 1u;
            const unsigned s1 = h01a[p] & 1u;
            const unsigned v00 = s0 ? pr0[p].y : pr0[p].x;
            const unsigned v01 = s1 ? pr1[p].y : pr1[p].x;
            const unsigned v10 = oddp[p] ? t10[p] : (s0 ? pr0[p].x : pr0[p].y);
            const unsigned v11 = oddp[p] ? t11[p] : (s1 ? pr1[p].x : pr1[p].y);
            const float wx = wxs[p], wy = wys[p];
            const float w00 = (1.0f - wx) * (1.0f - wy);
            const float w10 = wx * (1.0f - wy);
            const float w01 = (1.0f - wx) * wy;
            const float w11 = wx * wy;
            const float2 f00 = unpack_bf16x2(v00);
            const float2 f10 = unpack_bf16x2(v10);
            const float2 f01 = unpack_bf16x2(v01);
            const float2 f11 = unpack_bf16x2(v11);
            const float e0 = f00.x * w00 + f10.x * w10 + f01.x * w01 + f11.x * w11;
            const float e1 = f00.y * w00 + f10.y * w10 + f01.y * w01 + f11.y * w11;
            r[p] = pack_bf16x2(e0, e1);
        }
        __builtin_nontemporal_store(r, &((uint4v*)we)[gid]);
    } else {
        for (int p = 0; p < 4 && base + p < N; ++p) {
            const float2 c = reinterpret_cast<const float2*>(coords)[base + p];
            const float px = c.x * (float)res;
            const float py = c.y * (float)res;
            const float fx = floorf(px), fy = floorf(py);
            const float wx = px - fx, wy = py - fy;
            const unsigned ux = (unsigned)(int)fx, uy = (unsigned)(int)fy;
            const unsigned hy0 = uy * PRIME_Y;
            const unsigned hy1 = (uy + 1u) * PRIME_Y;
            const float2 v00 = unpack_bf16x2(tl[(ux ^ hy0) & (TSIZE - 1u)]);
            const float2 v10 = unpack_bf16x2(tl[((ux + 1u) ^ hy0) & (TSIZE - 1u)]);
            const float2 v01 = unpack_bf16x2(tl[(ux ^ hy1) & (TSIZE - 1u)]);
            const float2 v11 = unpack_bf16x2(tl[((ux + 1u) ^ hy1) & (TSIZE - 1u)]);
            const float w00 = (1.0f - wx) * (1.0f - wy);
            const float w10 = wx * (1.0f - wy);
            const float w01 = (1.0f - wx) * wy;
            const float w11 = wx * wy;
            const float e0 = v00.x * w00 + v10.x * w10 + v01.x * w01 + v11.x * w11;
            const float e1 = v00.y * w00 + v10.y * w10 + v01.y * w01 + v11.y * w11;
            we[base + p] = pack_bf16x2(e0, e1);
        }
    }
}

// ---- final: dense levels (16B row loads) + hashed enc from ws + MFMA SIREN MLP.
__global__ __launch_bounds__(64) void mlp_kernel(
    const float* __restrict__ coords,
    const float* __restrict__ table,
    const unsigned* __restrict__ wenc,
    const uint4v* __restrict__ wfrag,
    const float* __restrict__ b3p,
    float* __restrict__ out, int N)
{
    __shared__ char lds[5120];              // 64 rows x 80 B
    const int lane = threadIdx.x;
    const int n = lane & 15;
    const int kb = lane >> 4;

    // B-fragments: 6 coalesced b128 loads (built once by setup_kernel)
    union { short8 s; uint4v u; } c0, c1, c2, c3, c4;
    c0.u = wfrag[0 * 64 + lane];
    c1.u = wfrag[1 * 64 + lane];
    c2.u = wfrag[2 * 64 + lane];
    c3.u = wfrag[3 * 64 + lane];
    c4.u = wfrag[4 * 64 + lane];
    const short8 bf0 = c0.s, b1a = c1.s, b1b = c2.s, b2a = c3.s, b2b = c4.s;
    union { float4v f; uint4v u; } cf;
    cf.u = wfrag[5 * 64 + lane];
    const float b0n = cf.f.x, b1n = cf.f.y, b2n = cf.f.z, w3n = cf.f.w;
    const float b3s = b3p[0];

    const int idx = blockIdx.x * 64 + lane;
    const int idxc = (idx < N) ? idx : (N - 1);

    // hashed-enc streaming loads first (stay in flight over dense interp)
    unsigned he[NHASH];
    #pragma unroll
    for (int l = 0; l < NHASH; ++l)
        he[l] = __builtin_nontemporal_load(&wenc[(size_t)l * N + idxc]);

    const float2 c = reinterpret_cast<const float2*>(coords)[idxc];

    float enc[24];
    #pragma unroll
    for (int lvl = 0; lvl < 6; ++lvl) {
        const int res = 16 << lvl;
        const float px = c.x * (float)res;
        const float py = c.y * (float)res;
        const float fx = floorf(px), fy = floorf(py);
        const float wx = px - fx, wy = py - fy;
        const int ix = (int)fx, iy = (int)fy;
        const int stride = res + 1;
        const int base = ix + iy * stride;
        const float* __restrict__ tl = table + (size_t)lvl * TSIZE * 2u;
        // one 16B row load covers both x-corners (entries are 8B, adjacent)
        const f4a8 r0 = *reinterpret_cast<const f4a8*>(tl + 2 * (size_t)base);
        const f4a8 r1 = *reinterpret_cast<const f4a8*>(tl + 2 * (size_t)(base + stride));
        const float w00 = (1.0f - wx) * (1.0f - wy);
        const float w10 = wx * (1.0f - wy);
        const float w01 = (1.0f - wx) * wy;
        const float w11 = wx * wy;
        enc[2 * lvl]     = r0.x * w00 + r0.z * w10 + r1.x * w01 + r1.z * w11;
        enc[2 * lvl + 1] = r0.y * w00 + r0.w * w10 + r1.y * w01 + r1.w * w11;
    }
    #pragma unroll
    for (int l = 0; l < NHASH; ++l) {
        const float2 v = unpack_bf16x2(he[l]);
        enc[12 + 2 * l]     = v.x;
        enc[12 + 2 * l + 1] = v.y;
    }

    // ---- stage enc as bf16, K padded 24->32, row = lane (80 B stride)
    unsigned u[12];
    #pragma unroll
    for (int k = 0; k < 12; ++k) u[k] = pack_bf16x2(enc[2 * k], enc[2 * k + 1]);
    {
        uint4v* rowp = (uint4v*)(lds + lane * 80);
        uint4v r0; r0.x = u[0]; r0.y = u[1]; r0.z = u[2]; r0.w = u[3];
        uint4v r1; r1.x = u[4]; r1.y = u[5]; r1.z = u[6]; r1.w = u[7];
        uint4v r2; r2.x = u[8]; r2.y = u[9]; r2.z = u[10]; r2.w = u[11];
        uint4v r3; r3.x = 0u; r3.y = 0u; r3.z = 0u; r3.w = 0u;  // keep: no NaN*0
        rowp[0] = r0; rowp[1] = r1; rowp[2] = r2; rowp[3] = r3;
    }
    __syncthreads();

    short8 a[4];
    #pragma unroll
    for (int m = 0; m < 4; ++m)
        a[m] = *(const short8*)(lds + (m * 16 + n) * 80 + kb * 16);
    __syncthreads();

    const f32x4 z = {0.f, 0.f, 0.f, 0.f};
    f32x4 acc[4];
    #pragma unroll
    for (int m = 0; m < 4; ++m)
        acc[m] = __builtin_amdgcn_mfma_f32_16x16x32_bf16(a[m], bf0, z, 0, 0, 0);

    unsigned* hp32 = (unsigned*)lds;   // rows of 20 words; word n = {hi_n | lo_n<<16}

    // ---- layer 1: h0 = sin(300*(acc+b0)); packed hi|lo write; mfma hi+lo
    #pragma unroll
    for (int m = 0; m < 4; ++m) {
        #pragma unroll
        for (int r = 0; r < 4; ++r) {
            const float v = __sinf(300.0f * (acc[m][r] + b0n));
            const short hi = f2bf(v);
            const short lo = f2bf(v - bf2f(hi));
            const int row = m * 16 + kb * 4 + r;
            hp32[row * 20 + n] =
                ((unsigned)(unsigned short)hi) | (((unsigned)(unsigned short)lo) << 16);
        }
    }
    __syncthreads();
    #pragma unroll
    for (int m = 0; m < 4; ++m)
        a[m] = *(const short8*)(lds + (m * 16 + n) * 80 + kb * 16);
    __syncthreads();
    #pragma unroll
    for (int m = 0; m < 4; ++m) {
        f32x4 p = __builtin_amdgcn_mfma_f32_16x16x32_bf16(a[m], b1a, z, 0, 0, 0);
        acc[m] = __builtin_amdgcn_mfma_f32_16x16x32_bf16(a[m], b1b, p, 0, 0, 0);
    }

    // ---- layer 2
    #pragma unroll
    for (int m = 0; m < 4; ++m) {
        #pragma unroll
        for (int r = 0; r < 4; ++r) {
            const float v = __sinf(acc[m][r] + b1n);
            const short hi = f2bf(v);
            const short lo = f2bf(v - bf2f(hi));
            const int row = m * 16 + kb * 4 + r;
            hp32[row * 20 + n] =
                ((unsigned)(unsigned short)hi) | (((unsigned)(unsigned short)lo) << 16);
        }
    }
    __syncthreads();
    #pragma unroll
    for (int m = 0; m < 4; ++m)
        a[m] = *(const short8*)(lds + (m * 16 + n) * 80 + kb * 16);
    __syncthreads();
    #pragma unroll
    for (int m = 0; m < 4; ++m) {
        f32x4 p = __builtin_amdgcn_mfma_f32_16x16x32_bf16(a[m], b2a, z, 0, 0, 0);
        acc[m] = __builtin_amdgcn_mfma_f32_16x16x32_bf16(a[m], b2b, p, 0, 0, 0);
    }

    // ---- layer 3 (final, 16->1) in f32: h2 = sin(acc+b2); o = h2@W3 + b3
    float red[4][4];
    #pragma unroll
    for (int m = 0; m < 4; ++m) {
        #pragma unroll
        for (int r = 0; r < 4; ++r) {
            float v = __sinf(acc[m][r] + b2n) * w3n;
            v += __shfl_xor(v, 1);
            v += __shfl_xor(v, 2);
            v += __shfl_xor(v, 4);
            v += __shfl_xor(v, 8);
            red[m][r] = v;     // identical across the 16 lanes of group kb
        }
    }
    const int m2 = n >> 2, r2 = n & 3;
    float ov = 0.f;
    #pragma unroll
    for (int m = 0; m < 4; ++m) {
        #pragma unroll
        for (int r = 0; r < 4; ++r)
            if (m == m2 && r == r2) ov = red[m][r];   // static idx -> cndmask
    }
    const int gidx = blockIdx.x * 64 + m2 * 16 + kb * 4 + r2;
    if (gidx < N) out[gidx] = ov + b3s;
}

// ---- fallback: R1 fused kernel (known-good) for small ws
__global__ __launch_bounds__(256) void hashsiren_fused(
    const float* __restrict__ coords,
    const float* __restrict__ table,
    const float* __restrict__ W0, const float* __restrict__ b0,
    const float* __restrict__ W1, const float* __restrict__ b1,
    const float* __restrict__ W2, const float* __restrict__ b2,
    const float* __restrict__ W3, const float* __restrict__ b3,
    float* __restrict__ out, int N)
{
    __shared__ float sW0[384];
    __shared__ float sW1[256];
    __shared__ float sW2[256];
    __shared__ float sb0[16], sb1[16], sb2[16], sW3[16];
    __shared__ float sb3;

    const int t = threadIdx.x;
    for (int i = t; i < 384; i += 256) sW0[i] = W0[i];
    sW1[t] = W1[t];
    sW2[t] = W2[t];
    if (t < 16) { sb0[t] = b0[t]; sb1[t] = b1[t]; sb2[t] = b2[t]; sW3[t] = W3[t]; }
    if (t == 0) sb3 = b3[0];
    __syncthreads();

    const int idx = blockIdx.x * 256 + t;
    if (idx >= N) return;

    const float2 c = reinterpret_cast<const float2*>(coords)[idx];

    float2 hv00[6], hv10[6], hv01[6], hv11[6];
    float hwx[6], hwy[6];
    #pragma unroll
    for (int l = 0; l < 6; ++l) {
        const int res = 16 << (l + 6);
        const float px = c.x * (float)res;
        const float py = c.y * (float)res;
        const float fx = floorf(px), fy = floorf(py);
        hwx[l] = px - fx;
        hwy[l] = py - fy;
        const unsigned ux = (unsigned)(int)fx, uy = (unsigned)(int)fy;
        const unsigned hy0 = uy * PRIME_Y;
        const unsigned hy1 = (uy + 1u) * PRIME_Y;
        const float2* __restrict__ tl =
            reinterpret_cast<const float2*>(table) + (size_t)(l + 6) * TSIZE;
        hv00[l] = tl[(ux ^ hy0) & (TSIZE - 1u)];
        hv10[l] = tl[((ux + 1u) ^ hy0) & (TSIZE - 1u)];
        hv01[l] = tl[(ux ^ hy1) & (TSIZE - 1u)];
        hv11[l] = tl[((ux + 1u) ^ hy1) & (TSIZE - 1u)];
    }

    float enc[24];
    #pragma unroll
    for (int lvl = 0; lvl < 6; ++lvl) {
        const int res = 16 << lvl;
        const float px = c.x * (float)res;
        const float py = c.y * (float)res;
        const float fx = floorf(px), fy = floorf(py);
        const float wx = px - fx, wy = py - fy;
        const int ix = (int)fx, iy = (int)fy;
        const int stride = res + 1;
        const int base = ix + iy * stride;
        const float2* __restrict__ tl =
            reinterpret_cast<const float2*>(table) + (size_t)lvl * TSIZE;
        const float2 v00 = tl[base];
        const float2 v10 = tl[base + 1];
        const float2 v01 = tl[base + stride];
        const float2 v11 = tl[base + stride + 1];
        const float w00 = (1.0f - wx) * (1.0f - wy);
        const float w10 = wx * (1.0f - wy);
        const float w01 = (1.0f - wx) * wy;
        const float w11 = wx * wy;
        enc[2 * lvl]     = v00.x * w00 + v10.x * w10 + v01.x * w01 + v11.x * w11;
        enc[2 * lvl + 1] = v00.y * w00 + v10.y * w10 + v01.y * w01 + v11.y * w11;
    }
    #pragma unroll
    for (int l = 0; l < 6; ++l) {
        const float wx = hwx[l], wy = hwy[l];
        const float w00 = (1.0f - wx) * (1.0f - wy);
        const float w10 = wx * (1.0f - wy);
        const float w01 = (1.0f - wx) * wy;
        const float w11 = wx * wy;
        enc[2 * (l + 6)]     = hv00[l].x * w00 + hv10[l].x * w10 + hv01[l].x * w01 + hv11[l].x * w11;
        enc[2 * (l + 6) + 1] = hv00[l].y * w00 + hv10[l].y * w10 + hv01[l].y * w01 + hv11[l].y * w11;
    }

    float h0[16];
    #pragma unroll
    for (int j = 0; j < 16; ++j) {
        float aa = sb0[j];
        #pragma unroll
        for (int k = 0; k < 24; ++k) aa += enc[k] * sW0[k * 16 + j];
        h0[j] = __sinf(300.0f * aa);
    }
    float h1[16];
    #pragma unroll
    for (int j = 0; j < 16; ++j) {
        float aa = sb1[j];
        #pragma unroll
        for (int k = 0; k < 16; ++k) aa += h0[k] * sW1[k * 16 + j];
        h1[j] = __sinf(aa);
    }
    float h2[16];
    #pragma unroll
    for (int j = 0; j < 16; ++j) {
        float aa = sb2[j];
        #pragma unroll
        for (int k = 0; k < 16; ++k) aa += h1[k] * sW2[k * 16 + j];
        h2[j] = __sinf(aa);
    }
    float o = sb3;
    #pragma unroll
    for (int k = 0; k < 16; ++k) o += h2[k] * sW3[k];
    out[idx] = o;
}

extern "C" void kernel_launch(void* const* d_in, const int* in_sizes, int n_in,
                              void* d_out, int out_size, void* d_ws, size_t ws_size,
                              hipStream_t stream) {
    const float* coords = (const float*)d_in[0];
    const float* table  = (const float*)d_in[1];
    const float* W0 = (const float*)d_in[2];
    const float* b0 = (const float*)d_in[3];
    const float* W1 = (const float*)d_in[4];
    const float* b1 = (const float*)d_in[5];
    const float* W2 = (const float*)d_in[6];
    const float* b2 = (const float*)d_in[7];
    const float* W3 = (const float*)d_in[8];
    const float* b3 = (const float*)d_in[9];
    float* out = (float*)d_out;

    const int N = in_sizes[0] / 2;  // coords is [N,2]

    const size_t tab_w = (size_t)NHASH * TSIZE;          // u32 words
    const size_t enc_w = (size_t)NHASH * (size_t)N;      // u32 words
    const size_t need = tab_w * 4 + enc_w * 4 + 6144;    // + wfrag
    if (ws_size >= need) {
        unsigned* wtab = (unsigned*)d_ws;
        unsigned* wenc = wtab + tab_w;
        uint4v* wfrag = (uint4v*)(wenc + enc_w);
        setup_kernel<<<1, 64, 0, stream>>>(W0, b0, W1, b1, W2, b2, W3, wfrag);
        convert_kernel<<<4096, 256, 0, stream>>>(table, wtab);
        const int pgrid = (N + 1023) / 1024;
        for (int l = 0; l < NHASH; ++l)
            pass_kernel<<<pgrid, 256, 0, stream>>>(coords, wtab, wenc, l, N);
        mlp_kernel<<<(N + 63) / 64, 64, 0, stream>>>(coords, table, wenc, wfrag,
                                                     b3, out, N);
    } else {
        const int block = 256;
        const int grid = (N + block - 1) / block;
        hashsiren_fused<<<grid, block, 0, stream>>>(coords, table,
                                                    W0, b0, W1, b1, W2, b2, W3, b3,
                                                    out, N);
    }
}